// Round 1
// baseline (1072.291 us; speedup 1.0000x reference)
//
#include <hip/hip_runtime.h>
#include <cstdint>

typedef __bf16 bf16;
typedef __attribute__((ext_vector_type(4))) __bf16 bf16x4;
typedef __attribute__((ext_vector_type(8))) __bf16 bf16x8;
typedef __attribute__((ext_vector_type(4))) float f32x4;

#define DEVI __device__ __forceinline__

// Constants for this problem
#define BATCH 2
#define SEQ 2048
#define HID 4096
#define NH 32
#define NKVH 8
#define HD 128
#define QKVN 6144   // 4096 q + 1024 k + 1024 v
#define MROWS 4096  // B*S
#define ATT_SCALE 0.08838834764831845f

DEVI void gload_lds16(const bf16* g, bf16* l) {
  __builtin_amdgcn_global_load_lds(
      (__attribute__((address_space(1))) void*)(g),
      (__attribute__((address_space(3))) void*)(l), 16, 0, 0);
}

// ---------------- elementwise f32 -> bf16 ----------------
__global__ void h2b_kernel(const float* __restrict__ in, bf16* __restrict__ out) {
  long i = ((long)blockIdx.x * 256 + threadIdx.x) * 4;
  float4 v = *(const float4*)(in + i);
  bf16x4 o;
  o[0] = (bf16)v.x; o[1] = (bf16)v.y; o[2] = (bf16)v.z; o[3] = (bf16)v.w;
  *(bf16x4*)(out + i) = o;
}

// ---------------- transpose-convert weight: in (K,N) f32 -> out (N,K) bf16 ----------------
__global__ void wtrans_kernel(const float* __restrict__ in, bf16* __restrict__ out,
                              int K, int N) {
  __shared__ float t[32][33];
  int n0 = blockIdx.x * 32, k0 = blockIdx.y * 32;
  int tx = threadIdx.x, ty = threadIdx.y; // (32,8)
#pragma unroll
  for (int r = 0; r < 4; ++r) {
    int k = ty + r * 8;
    t[k][tx] = in[(long)(k0 + k) * N + n0 + tx];
  }
  __syncthreads();
#pragma unroll
  for (int r = 0; r < 4; ++r) {
    int n = ty + r * 8;
    out[(long)(n0 + n) * K + k0 + tx] = (bf16)t[tx][n];
  }
}

// ---------------- RoPE in-place on q,k columns of qkv ----------------
__global__ void rope_kernel(bf16* __restrict__ qkv, const int* __restrict__ pos) {
  long idx = (long)blockIdx.x * 256 + threadIdx.x;
  if (idx >= (long)MROWS * 40 * 64) return;
  int d = idx & 63;
  long t = idx >> 6;
  int hh = (int)(t % 40);
  int row = (int)(t / 40);
  int colb = hh < NH ? hh * HD : NH * HD + (hh - NH) * HD;
  float p = (float)pos[row];
  // inv_freq = 10000^(-d/64) = 2^(-d * log2(10000)/64)
  float inv_freq = exp2f((float)d * -0.2076205059304601f);
  float ang = p * inv_freq;
  float sn = sinf(ang), cs = cosf(ang);
  bf16* base = qkv + (long)row * QKVN + colb + d;
  float x1 = (float)base[0], x2 = (float)base[64];
  base[0] = (bf16)(x1 * cs - x2 * sn);
  base[64] = (bf16)(x2 * cs + x1 * sn);
}

// ---------------- transpose V: qkv v-cols -> vt (b,kvh,D,S) ----------------
__global__ void vtrans_kernel(const bf16* __restrict__ qkv, bf16* __restrict__ vt) {
  __shared__ bf16 t[32][33];
  int s0 = blockIdx.x * 32, d0 = blockIdx.y * 32, bk = blockIdx.z;
  int b = bk >> 3, kvh = bk & 7;
  int tx = threadIdx.x, ty = threadIdx.y; // (32,8)
#pragma unroll
  for (int r = 0; r < 4; ++r) {
    int s = ty + r * 8;
    t[s][tx] = qkv[(long)(b * SEQ + s0 + s) * QKVN + 5120 + kvh * HD + d0 + tx];
  }
  __syncthreads();
#pragma unroll
  for (int r = 0; r < 4; ++r) {
    int d = ty + r * 8;
    vt[((long)bk * HD + d0 + d) * SEQ + s0 + tx] = t[tx][d];
  }
}

// ---------------- GEMM: C(M,N) = A(M,K) x BT(N,K)^T, bf16 in, OutT out ----------------
// 128x128 tile, BK=64, 4 waves (2x2), m97-style structure.
template <typename OutT>
__global__ __launch_bounds__(256)
void gemm_bt(const bf16* __restrict__ A, const bf16* __restrict__ BT,
             OutT* __restrict__ C, int M, int N, int K) {
  __shared__ __align__(16) bf16 As[128 * 64];
  __shared__ __align__(16) bf16 Bs[128 * 64];
  const int tid = threadIdx.x;
  const int lane = tid & 63, wave = tid >> 6;
  const int wm = wave >> 1, wn = wave & 1;
  const int tm0 = blockIdx.y * 128, tn0 = blockIdx.x * 128;
  const int l16 = lane & 15, lhi = lane >> 4;
  const int arow = lane >> 3;          // row within 8-row chunk
  const int acol = (lane & 7) * 8;     // element col within BK

  f32x4 acc[4][4] = {};

  for (int k0 = 0; k0 < K; k0 += 64) {
#pragma unroll
    for (int c = 0; c < 4; ++c) {
      int chunk = wave * 4 + c;
      const bf16* ga = A + (long)(tm0 + chunk * 8 + arow) * K + k0 + acol;
      gload_lds16(ga, As + chunk * 512);
      const bf16* gb = BT + (long)(tn0 + chunk * 8 + arow) * K + k0 + acol;
      gload_lds16(gb, Bs + chunk * 512);
    }
    __syncthreads();
#pragma unroll
    for (int kk = 0; kk < 2; ++kk) {
      bf16x8 af[4], bfr[4];
#pragma unroll
      for (int i = 0; i < 4; ++i) {
        af[i] = *(const bf16x8*)(As + (wm * 64 + i * 16 + l16) * 64 + kk * 32 + lhi * 8);
        bfr[i] = *(const bf16x8*)(Bs + (wn * 64 + i * 16 + l16) * 64 + kk * 32 + lhi * 8);
      }
#pragma unroll
      for (int i = 0; i < 4; ++i)
#pragma unroll
        for (int j = 0; j < 4; ++j)
          acc[i][j] = __builtin_amdgcn_mfma_f32_16x16x32_bf16(af[i], bfr[j], acc[i][j], 0, 0, 0);
    }
    __syncthreads();
  }
  // epilogue: C layout col=lane&15, row=(lane>>4)*4+r (m89-verified)
#pragma unroll
  for (int i = 0; i < 4; ++i) {
#pragma unroll
    for (int r = 0; r < 4; ++r) {
      long grow = tm0 + wm * 64 + i * 16 + lhi * 4 + r;
#pragma unroll
      for (int j = 0; j < 4; ++j) {
        int gcol = tn0 + wn * 64 + j * 16 + l16;
        C[grow * N + gcol] = (OutT)acc[i][j][r];
      }
    }
  }
}

// ---------------- flash attention, causal, GQA ----------------
// grid (qt=S/64, h=32, b=2), 256 threads = 4 waves, each wave owns 16 q rows.
__global__ __launch_bounds__(256)
void attn_kernel(const bf16* __restrict__ qkv, const bf16* __restrict__ vt,
                 bf16* __restrict__ out) {
  __shared__ __align__(16) bf16 Ks[64 * 128];
  __shared__ __align__(16) bf16 Vs[128 * 64];
  __shared__ __align__(16) bf16 Ps[4][16 * 64];
  const int qt = blockIdx.x, h = blockIdx.y, b = blockIdx.z;
  const int kvh = h >> 2;
  const int tid = threadIdx.x, lane = tid & 63, wave = tid >> 6;
  const int l16 = lane & 15, lhi = lane >> 4;

  // Q fragments: rows qt*64 + wave*16 + (0..15), all 128 d
  bf16x8 qf[4];
  const bf16* qbase = qkv + (long)(b * SEQ + qt * 64 + wave * 16 + l16) * QKVN + h * HD + lhi * 8;
#pragma unroll
  for (int di = 0; di < 4; ++di) qf[di] = *(const bf16x8*)(qbase + di * 32);

  f32x4 oacc[8] = {};
  float m_run[4], l_run[4];
#pragma unroll
  for (int r = 0; r < 4; ++r) { m_run[r] = -1e30f; l_run[r] = 0.f; }
  const int qrow = qt * 64 + wave * 16 + lhi * 4; // + r

  const int nsteps = qt + 1;
  for (int step = 0; step < nsteps; ++step) {
    const int kv0 = step * 64;
    // stage K (64x128) and V^T (128x64) tiles
#pragma unroll
    for (int c = 0; c < 4; ++c) {
      int chunk = wave * 4 + c;
      int krow = chunk * 4 + lhi;
      const bf16* gk = qkv + (long)(b * SEQ + kv0 + krow) * QKVN + 4096 + kvh * HD + l16 * 8;
      gload_lds16(gk, Ks + chunk * 512);
      int vrow = chunk * 8 + (lane >> 3);
      const bf16* gv = vt + ((long)(b * NKVH + kvh) * HD + vrow) * SEQ + kv0 + (lane & 7) * 8;
      gload_lds16(gv, Vs + chunk * 512);
    }
    __syncthreads();

    // QK^T: scores 16x64 as 4 col-tiles
    f32x4 s[4];
#pragma unroll
    for (int c = 0; c < 4; ++c) {
      s[c] = (f32x4){0.f, 0.f, 0.f, 0.f};
#pragma unroll
      for (int di = 0; di < 4; ++di) {
        bf16x8 kf = *(const bf16x8*)(Ks + (c * 16 + l16) * 128 + di * 32 + lhi * 8);
        s[c] = __builtin_amdgcn_mfma_f32_16x16x32_bf16(qf[di], kf, s[c], 0, 0, 0);
      }
    }
    // scale + causal mask
#pragma unroll
    for (int c = 0; c < 4; ++c) {
      int col = kv0 + c * 16 + l16;
#pragma unroll
      for (int r = 0; r < 4; ++r) {
        float v = s[c][r] * ATT_SCALE;
        s[c][r] = (col <= qrow + r) ? v : -1e30f;
      }
    }
    // online softmax (row r lives across lanes with same lhi, col = l16)
    float alpha[4];
#pragma unroll
    for (int r = 0; r < 4; ++r) {
      float m = fmaxf(fmaxf(s[0][r], s[1][r]), fmaxf(s[2][r], s[3][r]));
#pragma unroll
      for (int off = 1; off < 16; off <<= 1)
        m = fmaxf(m, __shfl_xor(m, off, 64));
      float mn = fmaxf(m_run[r], m);
      alpha[r] = __expf(m_run[r] - mn);
      m_run[r] = mn;
      float sm = 0.f;
#pragma unroll
      for (int c = 0; c < 4; ++c) {
        float p = __expf(s[c][r] - mn);
        s[c][r] = p;
        sm += p;
      }
#pragma unroll
      for (int off = 1; off < 16; off <<= 1)
        sm += __shfl_xor(sm, off, 64);
      l_run[r] = l_run[r] * alpha[r] + sm;
    }
    // write P to wave-private LDS (C-layout -> row-major [16][64])
#pragma unroll
    for (int c = 0; c < 4; ++c)
#pragma unroll
      for (int r = 0; r < 4; ++r)
        Ps[wave][(lhi * 4 + r) * 64 + c * 16 + l16] = (bf16)s[c][r];
    // rescale O
#pragma unroll
    for (int dj = 0; dj < 8; ++dj)
#pragma unroll
      for (int r = 0; r < 4; ++r) oacc[dj][r] *= alpha[r];
    // PV: O[16][128] += P[16][64] x V[64][128]
#pragma unroll
    for (int kh = 0; kh < 2; ++kh) {
      bf16x8 pf = *(const bf16x8*)(&Ps[wave][l16 * 64 + kh * 32 + lhi * 8]);
#pragma unroll
      for (int dj = 0; dj < 8; ++dj) {
        bf16x8 vf = *(const bf16x8*)(Vs + (dj * 16 + l16) * 64 + kh * 32 + lhi * 8);
        oacc[dj] = __builtin_amdgcn_mfma_f32_16x16x32_bf16(pf, vf, oacc[dj], 0, 0, 0);
      }
    }
    __syncthreads();
  }
  // epilogue: normalize and store bf16
#pragma unroll
  for (int r = 0; r < 4; ++r) {
    float inv = 1.f / l_run[r];
    long orow = (long)(b * SEQ + qt * 64 + wave * 16 + lhi * 4 + r);
#pragma unroll
    for (int dj = 0; dj < 8; ++dj)
      out[orow * (NH * HD) + h * HD + dj * 16 + l16] = (bf16)(oacc[dj][r] * inv);
  }
}

extern "C" void kernel_launch(void* const* d_in, const int* in_sizes, int n_in,
                              void* d_out, int out_size, void* d_ws, size_t ws_size,
                              hipStream_t stream) {
  const int* positions = (const int*)d_in[0];
  const float* hidden = (const float*)d_in[1];
  const float* wq = (const float*)d_in[2];
  const float* wk = (const float*)d_in[3];
  const float* wv = (const float*)d_in[4];
  const float* wo = (const float*)d_in[5];
  float* out = (float*)d_out;
  char* ws = (char*)d_ws;

  // workspace layout (bytes)
  const size_t SZ_H = (size_t)MROWS * HID * 2;       // 32MB hidden bf16
  const size_t SZ_WQKV = (size_t)QKVN * HID * 2;     // 48MB wqkv^T bf16
  const size_t SZ_WO = (size_t)HID * HID * 2;        // 32MB wo^T bf16
  bf16* h_bf = (bf16*)(ws);
  bf16* wqkvT = (bf16*)(ws + SZ_H);
  bf16* woT = (bf16*)(ws + SZ_H + SZ_WQKV);
  bf16* qkv = (bf16*)(ws + SZ_H + SZ_WQKV + SZ_WO);  // 48MB
  bf16* attn = h_bf;    // alias: hidden bf16 dead after GEMM1
  bf16* vtbuf = wqkvT;  // alias: wqkv^T dead after GEMM1

  // 1. hidden f32 -> bf16
  h2b_kernel<<<(MROWS * (long)HID) / (256 * 4), 256, 0, stream>>>(hidden, h_bf);
  // 2. weight transposes (f32 (K,N) -> bf16 (N,K))
  dim3 t32(32, 8);
  wtrans_kernel<<<dim3(HID / 32, HID / 32), t32, 0, stream>>>(wq, wqkvT, HID, HID);
  wtrans_kernel<<<dim3(1024 / 32, HID / 32), t32, 0, stream>>>(wk, wqkvT + (long)4096 * HID, HID, 1024);
  wtrans_kernel<<<dim3(1024 / 32, HID / 32), t32, 0, stream>>>(wv, wqkvT + (long)5120 * HID, HID, 1024);
  wtrans_kernel<<<dim3(HID / 32, HID / 32), t32, 0, stream>>>(wo, woT, HID, HID);
  // 3. QKV projection
  gemm_bt<bf16><<<dim3(QKVN / 128, MROWS / 128), 256, 0, stream>>>(h_bf, wqkvT, qkv, MROWS, QKVN, HID);
  // 4. RoPE in-place on q,k
  rope_kernel<<<(MROWS * 40 * 64) / 256, 256, 0, stream>>>(qkv, positions);
  // 5. V transpose -> (b,kvh,D,S)
  vtrans_kernel<<<dim3(SEQ / 32, HD / 32, BATCH * NKVH), t32, 0, stream>>>(qkv, vtbuf);
  // 6. flash attention
  attn_kernel<<<dim3(SEQ / 64, NH, BATCH), 256, 0, stream>>>(qkv, vtbuf, attn);
  // 7. output projection -> f32 out
  gemm_bt<float><<<dim3(HID / 128, MROWS / 128), 256, 0, stream>>>(attn, woT, out, MROWS, HID, HID);
}

// Round 2
// 889.035 us; speedup vs baseline: 1.2061x; 1.2061x over previous
//
#include <hip/hip_runtime.h>
#include <cstdint>

typedef __bf16 bf16;
typedef __attribute__((ext_vector_type(4))) __bf16 bf16x4;
typedef __attribute__((ext_vector_type(8))) __bf16 bf16x8;
typedef __attribute__((ext_vector_type(4))) float f32x4;

#define DEVI __device__ __forceinline__

// Constants for this problem
#define BATCH 2
#define SEQ 2048
#define HID 4096
#define NH 32
#define NKVH 8
#define HD 128
#define QKVN 6144   // 4096 q + 1024 k + 1024 v
#define MROWS 4096  // B*S
#define ATT_SCALE 0.08838834764831845f

DEVI void gload_lds16(const bf16* g, bf16* l) {
  __builtin_amdgcn_global_load_lds(
      (__attribute__((address_space(1))) void*)(g),
      (__attribute__((address_space(3))) void*)(l), 16, 0, 0);
}

// ---------------- elementwise f32 -> bf16 ----------------
__global__ void h2b_kernel(const float* __restrict__ in, bf16* __restrict__ out) {
  long i = ((long)blockIdx.x * 256 + threadIdx.x) * 4;
  float4 v = *(const float4*)(in + i);
  bf16x4 o;
  o[0] = (bf16)v.x; o[1] = (bf16)v.y; o[2] = (bf16)v.z; o[3] = (bf16)v.w;
  *(bf16x4*)(out + i) = o;
}

// ---------------- transpose-convert weight: in (K,N) f32 -> out (N,K) bf16 ----------------
__global__ void wtrans_kernel(const float* __restrict__ in, bf16* __restrict__ out,
                              int K, int N) {
  __shared__ float t[32][33];
  int n0 = blockIdx.x * 32, k0 = blockIdx.y * 32;
  int tx = threadIdx.x, ty = threadIdx.y; // (32,8)
#pragma unroll
  for (int r = 0; r < 4; ++r) {
    int k = ty + r * 8;
    t[k][tx] = in[(long)(k0 + k) * N + n0 + tx];
  }
  __syncthreads();
#pragma unroll
  for (int r = 0; r < 4; ++r) {
    int n = ty + r * 8;
    out[(long)(n0 + n) * K + k0 + tx] = (bf16)t[tx][n];
  }
}

// ---------------- RoPE in-place on q,k columns of qkv ----------------
__global__ void rope_kernel(bf16* __restrict__ qkv, const int* __restrict__ pos) {
  long idx = (long)blockIdx.x * 256 + threadIdx.x;
  if (idx >= (long)MROWS * 40 * 64) return;
  int d = idx & 63;
  long t = idx >> 6;
  int hh = (int)(t % 40);
  int row = (int)(t / 40);
  int colb = hh < NH ? hh * HD : NH * HD + (hh - NH) * HD;
  float p = (float)pos[row];
  float inv_freq = exp2f((float)d * -0.2076205059304601f);
  float ang = p * inv_freq;
  float sn = sinf(ang), cs = cosf(ang);
  bf16* base = qkv + (long)row * QKVN + colb + d;
  float x1 = (float)base[0], x2 = (float)base[64];
  base[0] = (bf16)(x1 * cs - x2 * sn);
  base[64] = (bf16)(x2 * cs + x1 * sn);
}

// ---------------- transpose V: qkv v-cols -> vt (b,kvh,D,S) ----------------
__global__ void vtrans_kernel(const bf16* __restrict__ qkv, bf16* __restrict__ vt) {
  __shared__ bf16 t[32][33];
  int s0 = blockIdx.x * 32, d0 = blockIdx.y * 32, bk = blockIdx.z;
  int b = bk >> 3, kvh = bk & 7;
  int tx = threadIdx.x, ty = threadIdx.y; // (32,8)
#pragma unroll
  for (int r = 0; r < 4; ++r) {
    int s = ty + r * 8;
    t[s][tx] = qkv[(long)(b * SEQ + s0 + s) * QKVN + 5120 + kvh * HD + d0 + tx];
  }
  __syncthreads();
#pragma unroll
  for (int r = 0; r < 4; ++r) {
    int d = ty + r * 8;
    vt[((long)bk * HD + d0 + d) * SEQ + s0 + tx] = t[tx][d];
  }
}

// ---------------- GEMM: C(M,N) = A(M,K) x BT(N,K)^T, bf16 in, OutT out ----------------
template <typename OutT>
__global__ __launch_bounds__(256)
void gemm_bt(const bf16* __restrict__ A, const bf16* __restrict__ BT,
             OutT* __restrict__ C, int M, int N, int K) {
  __shared__ __align__(16) bf16 As[128 * 64];
  __shared__ __align__(16) bf16 Bs[128 * 64];
  const int tid = threadIdx.x;
  const int lane = tid & 63, wave = tid >> 6;
  const int wm = wave >> 1, wn = wave & 1;
  const int tm0 = blockIdx.y * 128, tn0 = blockIdx.x * 128;
  const int l16 = lane & 15, lhi = lane >> 4;
  const int arow = lane >> 3;
  const int acol = (lane & 7) * 8;

  f32x4 acc[4][4] = {};

  for (int k0 = 0; k0 < K; k0 += 64) {
#pragma unroll
    for (int c = 0; c < 4; ++c) {
      int chunk = wave * 4 + c;
      const bf16* ga = A + (long)(tm0 + chunk * 8 + arow) * K + k0 + acol;
      gload_lds16(ga, As + chunk * 512);
      const bf16* gb = BT + (long)(tn0 + chunk * 8 + arow) * K + k0 + acol;
      gload_lds16(gb, Bs + chunk * 512);
    }
    __syncthreads();
#pragma unroll
    for (int kk = 0; kk < 2; ++kk) {
      bf16x8 af[4], bfr[4];
#pragma unroll
      for (int i = 0; i < 4; ++i) {
        af[i] = *(const bf16x8*)(As + (wm * 64 + i * 16 + l16) * 64 + kk * 32 + lhi * 8);
        bfr[i] = *(const bf16x8*)(Bs + (wn * 64 + i * 16 + l16) * 64 + kk * 32 + lhi * 8);
      }
#pragma unroll
      for (int i = 0; i < 4; ++i)
#pragma unroll
        for (int j = 0; j < 4; ++j)
          acc[i][j] = __builtin_amdgcn_mfma_f32_16x16x32_bf16(af[i], bfr[j], acc[i][j], 0, 0, 0);
    }
    __syncthreads();
  }
#pragma unroll
  for (int i = 0; i < 4; ++i) {
#pragma unroll
    for (int r = 0; r < 4; ++r) {
      long grow = tm0 + wm * 64 + i * 16 + lhi * 4 + r;
#pragma unroll
      for (int j = 0; j < 4; ++j) {
        int gcol = tn0 + wn * 64 + j * 16 + l16;
        C[grow * N + gcol] = (OutT)acc[i][j][r];
      }
    }
  }
}

// ---------------- flash attention, causal, GQA, LDS-swizzled ----------------
// grid (qt=S/64 reversed, h=32, b=2), 256 threads = 4 waves, each wave owns 16 q rows.
// All LDS tiles use 16B-slot XOR swizzle: slot ^= (row & 7). global_load_lds keeps a
// LINEAR dest; the per-lane GLOBAL source column is pre-permuted with the same XOR.
__global__ __launch_bounds__(256)
void attn_kernel(const bf16* __restrict__ qkv, const bf16* __restrict__ vt,
                 bf16* __restrict__ out) {
  __shared__ __align__(16) bf16 Ks[64 * 128];
  __shared__ __align__(16) bf16 Vs[128 * 64];
  __shared__ __align__(16) bf16 Ps[4][16 * 64];
  const int qt = (gridDim.x - 1) - blockIdx.x;  // longest blocks first
  const int h = blockIdx.y, b = blockIdx.z;
  const int kvh = h >> 2;
  const int tid = threadIdx.x, lane = tid & 63, wave = tid >> 6;
  const int l16 = lane & 15, lhi = lane >> 4;

  // Q fragments: rows qt*64 + wave*16 + (0..15), all 128 d
  bf16x8 qf[4];
  const bf16* qbase = qkv + (long)(b * SEQ + qt * 64 + wave * 16 + l16) * QKVN + h * HD + lhi * 8;
#pragma unroll
  for (int di = 0; di < 4; ++di) qf[di] = *(const bf16x8*)(qbase + di * 32);

  f32x4 oacc[8] = {};
  float m_run[4], l_run[4];
#pragma unroll
  for (int r = 0; r < 4; ++r) { m_run[r] = -1e30f; l_run[r] = 0.f; }
  const int qrow = qt * 64 + wave * 16 + lhi * 4; // + r

  const int nsteps = qt + 1;
  for (int step = 0; step < nsteps; ++step) {
    const int kv0 = step * 64;
    // stage K (64x128, swizzled) and V^T (128x64, swizzled)
#pragma unroll
    for (int c = 0; c < 4; ++c) {
      int chunk = wave * 4 + c;
      int krow = chunk * 4 + lhi;             // lds dest row for this lane
      int kc16 = l16 ^ (krow & 7);            // pre-swizzled source 16B-slot
      const bf16* gk = qkv + (long)(b * SEQ + kv0 + krow) * QKVN + 4096 + kvh * HD + kc16 * 8;
      gload_lds16(gk, Ks + chunk * 512);
      int vrow = chunk * 8 + (lane >> 3);
      int vc16 = (lane & 7) ^ (vrow & 7);
      const bf16* gv = vt + ((long)(b * NKVH + kvh) * HD + vrow) * SEQ + kv0 + vc16 * 8;
      gload_lds16(gv, Vs + chunk * 512);
    }
    __syncthreads();

    // QK^T: scores 16x64 as 4 col-tiles
    f32x4 s[4];
    __builtin_amdgcn_s_setprio(1);
#pragma unroll
    for (int c = 0; c < 4; ++c) {
      s[c] = (f32x4){0.f, 0.f, 0.f, 0.f};
      int krow2 = c * 16 + l16;
#pragma unroll
      for (int di = 0; di < 4; ++di) {
        bf16x8 kf = *(const bf16x8*)(Ks + krow2 * 128 + (((di * 4 + lhi) ^ (krow2 & 7))) * 8);
        s[c] = __builtin_amdgcn_mfma_f32_16x16x32_bf16(qf[di], kf, s[c], 0, 0, 0);
      }
    }
    __builtin_amdgcn_s_setprio(0);
    // scale + causal mask
#pragma unroll
    for (int c = 0; c < 4; ++c) {
      int col = kv0 + c * 16 + l16;
#pragma unroll
      for (int r = 0; r < 4; ++r) {
        float v = s[c][r] * ATT_SCALE;
        s[c][r] = (col <= qrow + r) ? v : -1e30f;
      }
    }
    // online softmax (row r lives across lanes with same lhi, col = l16)
    float alpha[4];
#pragma unroll
    for (int r = 0; r < 4; ++r) {
      float m = fmaxf(fmaxf(s[0][r], s[1][r]), fmaxf(s[2][r], s[3][r]));
#pragma unroll
      for (int off = 1; off < 16; off <<= 1)
        m = fmaxf(m, __shfl_xor(m, off, 64));
      float mn = fmaxf(m_run[r], m);
      alpha[r] = __expf(m_run[r] - mn);
      m_run[r] = mn;
      float sm = 0.f;
#pragma unroll
      for (int c = 0; c < 4; ++c) {
        float p = __expf(s[c][r] - mn);
        s[c][r] = p;
        sm += p;
      }
#pragma unroll
      for (int off = 1; off < 16; off <<= 1)
        sm += __shfl_xor(sm, off, 64);
      l_run[r] = l_run[r] * alpha[r] + sm;
    }
    // write P to wave-private LDS (swizzled [16][64])
#pragma unroll
    for (int c = 0; c < 4; ++c)
#pragma unroll
      for (int r = 0; r < 4; ++r) {
        int prow = lhi * 4 + r;
        int sl = (2 * c + (l16 >> 3)) ^ (prow & 7);
        Ps[wave][prow * 64 + sl * 8 + (l16 & 7)] = (bf16)s[c][r];
      }
    // rescale O
#pragma unroll
    for (int dj = 0; dj < 8; ++dj)
#pragma unroll
      for (int r = 0; r < 4; ++r) oacc[dj][r] *= alpha[r];
    // PV: O[16][128] += P[16][64] x V[64][128]
    __builtin_amdgcn_s_setprio(1);
#pragma unroll
    for (int kh = 0; kh < 2; ++kh) {
      bf16x8 pf = *(const bf16x8*)(&Ps[wave][l16 * 64 + (((kh * 4 + lhi) ^ (l16 & 7))) * 8]);
#pragma unroll
      for (int dj = 0; dj < 8; ++dj) {
        int vrow2 = dj * 16 + l16;
        bf16x8 vf = *(const bf16x8*)(Vs + vrow2 * 64 + (((kh * 4 + lhi) ^ (vrow2 & 7))) * 8);
        oacc[dj] = __builtin_amdgcn_mfma_f32_16x16x32_bf16(pf, vf, oacc[dj], 0, 0, 0);
      }
    }
    __builtin_amdgcn_s_setprio(0);
    __syncthreads();
  }
  // epilogue: normalize and store bf16
#pragma unroll
  for (int r = 0; r < 4; ++r) {
    float inv = 1.f / l_run[r];
    long orow = (long)(b * SEQ + qt * 64 + wave * 16 + lhi * 4 + r);
#pragma unroll
    for (int dj = 0; dj < 8; ++dj)
      out[orow * (NH * HD) + h * HD + dj * 16 + l16] = (bf16)(oacc[dj][r] * inv);
  }
}

extern "C" void kernel_launch(void* const* d_in, const int* in_sizes, int n_in,
                              void* d_out, int out_size, void* d_ws, size_t ws_size,
                              hipStream_t stream) {
  const int* positions = (const int*)d_in[0];
  const float* hidden = (const float*)d_in[1];
  const float* wq = (const float*)d_in[2];
  const float* wk = (const float*)d_in[3];
  const float* wv = (const float*)d_in[4];
  const float* wo = (const float*)d_in[5];
  float* out = (float*)d_out;
  char* ws = (char*)d_ws;

  const size_t SZ_H = (size_t)MROWS * HID * 2;       // 32MB hidden bf16
  const size_t SZ_WQKV = (size_t)QKVN * HID * 2;     // 48MB wqkv^T bf16
  const size_t SZ_WO = (size_t)HID * HID * 2;        // 32MB wo^T bf16
  bf16* h_bf = (bf16*)(ws);
  bf16* wqkvT = (bf16*)(ws + SZ_H);
  bf16* woT = (bf16*)(ws + SZ_H + SZ_WQKV);
  bf16* qkv = (bf16*)(ws + SZ_H + SZ_WQKV + SZ_WO);  // 48MB
  bf16* attn = h_bf;    // alias: hidden bf16 dead after GEMM1
  bf16* vtbuf = wqkvT;  // alias: wqkv^T dead after GEMM1

  h2b_kernel<<<(MROWS * (long)HID) / (256 * 4), 256, 0, stream>>>(hidden, h_bf);
  dim3 t32(32, 8);
  wtrans_kernel<<<dim3(HID / 32, HID / 32), t32, 0, stream>>>(wq, wqkvT, HID, HID);
  wtrans_kernel<<<dim3(1024 / 32, HID / 32), t32, 0, stream>>>(wk, wqkvT + (long)4096 * HID, HID, 1024);
  wtrans_kernel<<<dim3(1024 / 32, HID / 32), t32, 0, stream>>>(wv, wqkvT + (long)5120 * HID, HID, 1024);
  wtrans_kernel<<<dim3(HID / 32, HID / 32), t32, 0, stream>>>(wo, woT, HID, HID);
  gemm_bt<bf16><<<dim3(QKVN / 128, MROWS / 128), 256, 0, stream>>>(h_bf, wqkvT, qkv, MROWS, QKVN, HID);
  rope_kernel<<<(MROWS * 40 * 64) / 256, 256, 0, stream>>>(qkv, positions);
  vtrans_kernel<<<dim3(SEQ / 32, HD / 32, BATCH * NKVH), t32, 0, stream>>>(qkv, vtbuf);
  attn_kernel<<<dim3(SEQ / 64, NH, BATCH), 256, 0, stream>>>(qkv, vtbuf, attn);
  gemm_bt<float><<<dim3(HID / 128, MROWS / 128), 256, 0, stream>>>(attn, woT, out, MROWS, HID, HID);
}

// Round 3
// 763.159 us; speedup vs baseline: 1.4051x; 1.1649x over previous
//
#include <hip/hip_runtime.h>
#include <cstdint>

typedef __bf16 bf16;
typedef __attribute__((ext_vector_type(4))) __bf16 bf16x4;
typedef __attribute__((ext_vector_type(8))) __bf16 bf16x8;
typedef __attribute__((ext_vector_type(4))) float f32x4;

#define DEVI __device__ __forceinline__

#define BATCH 2
#define SEQ 2048
#define HID 4096
#define NH 32
#define NKVH 8
#define HD 128
#define QKVN 6144
#define MROWS 4096
#define ATT_SCALE 0.08838834764831845f

DEVI void gload_lds16(const bf16* g, bf16* l) {
  __builtin_amdgcn_global_load_lds(
      (__attribute__((address_space(1))) void*)(g),
      (__attribute__((address_space(3))) void*)(l), 16, 0, 0);
}

// ---------------- elementwise f32 -> bf16 ----------------
__global__ void h2b_kernel(const float* __restrict__ in, bf16* __restrict__ out) {
  long i = ((long)blockIdx.x * 256 + threadIdx.x) * 4;
  float4 v = *(const float4*)(in + i);
  bf16x4 o;
  o[0] = (bf16)v.x; o[1] = (bf16)v.y; o[2] = (bf16)v.z; o[3] = (bf16)v.w;
  *(bf16x4*)(out + i) = o;
}

// ---------------- transpose-convert weight: in (K,N) f32 -> out (N,K) bf16 ----------------
__global__ void wtrans_kernel(const float* __restrict__ in, bf16* __restrict__ out,
                              int K, int N) {
  __shared__ float t[32][33];
  int n0 = blockIdx.x * 32, k0 = blockIdx.y * 32;
  int tx = threadIdx.x, ty = threadIdx.y; // (32,8)
#pragma unroll
  for (int r = 0; r < 4; ++r) {
    int k = ty + r * 8;
    t[k][tx] = in[(long)(k0 + k) * N + n0 + tx];
  }
  __syncthreads();
#pragma unroll
  for (int r = 0; r < 4; ++r) {
    int n = ty + r * 8;
    out[(long)(n0 + n) * K + k0 + tx] = (bf16)t[tx][n];
  }
}

// ---------------- RoPE in-place on q,k columns of qkv ----------------
__global__ void rope_kernel(bf16* __restrict__ qkv, const int* __restrict__ pos) {
  long idx = (long)blockIdx.x * 256 + threadIdx.x;
  if (idx >= (long)MROWS * 40 * 64) return;
  int d = idx & 63;
  long t = idx >> 6;
  int hh = (int)(t % 40);
  int row = (int)(t / 40);
  int colb = hh < NH ? hh * HD : NH * HD + (hh - NH) * HD;
  float p = (float)pos[row];
  float inv_freq = exp2f((float)d * -0.2076205059304601f);
  float ang = p * inv_freq;
  float sn = sinf(ang), cs = cosf(ang);
  bf16* base = qkv + (long)row * QKVN + colb + d;
  float x1 = (float)base[0], x2 = (float)base[64];
  base[0] = (bf16)(x1 * cs - x2 * sn);
  base[64] = (bf16)(x2 * cs + x1 * sn);
}

// ---------------- transpose V: qkv v-cols -> vt (b,kvh,D,S) ----------------
__global__ void vtrans_kernel(const bf16* __restrict__ qkv, bf16* __restrict__ vt) {
  __shared__ bf16 t[32][33];
  int s0 = blockIdx.x * 32, d0 = blockIdx.y * 32, bk = blockIdx.z;
  int b = bk >> 3, kvh = bk & 7;
  int tx = threadIdx.x, ty = threadIdx.y; // (32,8)
#pragma unroll
  for (int r = 0; r < 4; ++r) {
    int s = ty + r * 8;
    t[s][tx] = qkv[(long)(b * SEQ + s0 + s) * QKVN + 5120 + kvh * HD + d0 + tx];
  }
  __syncthreads();
#pragma unroll
  for (int r = 0; r < 4; ++r) {
    int d = ty + r * 8;
    vt[((long)bk * HD + d0 + d) * SEQ + s0 + tx] = t[tx][d];
  }
}

// ---------------- pipelined GEMM: C(M,N) = A(M,K) x BT(N,K)^T ----------------
// 256x128 tile, BK=64, 8 waves (4M x 2N), wave-tile 64x64.
// Ring-3 LDS slots of (A[256][64] + B[128][64]) bf16 = 48KB/slot, 144KB total (dynamic).
// Per tile: counted vmcnt(6) + raw barrier + sched_barrier, prefetch t+2 into the
// slot freed at this barrier, 16 swizzled ds_read_b128, 32 MFMA under setprio.
// 16B-slot XOR swizzle: LDS (r, s) holds global (r, s ^ (r&7)); stage pre-swizzles
// the GLOBAL source column (linear LDS dest per gload_lds rules), reads apply XOR.
template <typename OutT>
__global__ __launch_bounds__(512, 2)
void gemm256(const bf16* __restrict__ A, const bf16* __restrict__ BT,
             OutT* __restrict__ C, int M, int N, int K) {
  extern __shared__ __align__(16) bf16 lds[];
  const int tid = threadIdx.x;
  const int lane = tid & 63, wave = tid >> 6;
  const int wm = wave >> 1, wn = wave & 1;
  const int l16 = lane & 15, lhi = lane >> 4;
  // XCD-aware swizzle (nwg % 8 == 0 for both launch shapes)
  const int nwg = gridDim.x * gridDim.y;
  const int bid = blockIdx.y * gridDim.x + blockIdx.x;
  const int cpx = nwg >> 3;
  const int swz = (bid & 7) * cpx + (bid >> 3);
  const int bx = swz % gridDim.x, by = swz / gridDim.x;
  const long bm0 = (long)by * 256, bn0 = (long)bx * 128;

  const int srow8 = lane >> 3;            // 0..7 row within 8-row stripe
  const int scol = (lane & 7) ^ srow8;    // pre-swizzled source 16B-slot

  const int NT = K >> 6;
  f32x4 acc[4][4] = {};

  auto stage = [&](int slot, int t) {
    const long k0 = (long)t << 6;
    bf16* dst = lds + slot * 24576;
#pragma unroll
    for (int i = 0; i < 4; ++i) {
      int r = (wave * 4 + i) * 8 + srow8;
      gload_lds16(A + (bm0 + r) * K + k0 + scol * 8,
                  dst + (wave * 4 + i) * 512 + lane * 8);
    }
#pragma unroll
    for (int i = 0; i < 2; ++i) {
      int r = (wave * 2 + i) * 8 + srow8;
      gload_lds16(BT + (bn0 + r) * K + k0 + scol * 8,
                  dst + 16384 + (wave * 2 + i) * 512 + lane * 8);
    }
  };

  stage(0, 0);
  stage(1, 1);

  for (int t = 0; t < NT; ++t) {
    asm volatile("s_waitcnt vmcnt(6)" ::: "memory");  // tile t landed; t+1 in flight
    __builtin_amdgcn_s_barrier();
    __builtin_amdgcn_sched_barrier(0);
    const int nxt = (t + 2 < NT) ? t + 2 : NT - 1;    // dup-load tail keeps count uniform
    stage((t + 2) % 3, nxt);                          // slot freed by this barrier
    const bf16* As = lds + (t % 3) * 24576;
    const bf16* Bs = As + 16384;
#pragma unroll
    for (int kk = 0; kk < 2; ++kk) {
      bf16x8 af[4], bw[4];
#pragma unroll
      for (int i = 0; i < 4; ++i) {
        int ar = wm * 64 + i * 16 + l16;
        af[i] = *(const bf16x8*)(As + ar * 64 + (((kk * 4 + lhi) ^ (ar & 7))) * 8);
        int br = wn * 64 + i * 16 + l16;
        bw[i] = *(const bf16x8*)(Bs + br * 64 + (((kk * 4 + lhi) ^ (br & 7))) * 8);
      }
      __builtin_amdgcn_s_setprio(1);
#pragma unroll
      for (int i = 0; i < 4; ++i)
#pragma unroll
        for (int j = 0; j < 4; ++j)
          acc[i][j] = __builtin_amdgcn_mfma_f32_16x16x32_bf16(af[i], bw[j], acc[i][j], 0, 0, 0);
      __builtin_amdgcn_s_setprio(0);
    }
  }
  asm volatile("s_waitcnt vmcnt(0)" ::: "memory");  // drain tail dup loads
#pragma unroll
  for (int i = 0; i < 4; ++i)
#pragma unroll
    for (int r = 0; r < 4; ++r) {
      long grow = bm0 + wm * 64 + i * 16 + lhi * 4 + r;
#pragma unroll
      for (int j = 0; j < 4; ++j) {
        long gcol = bn0 + wn * 64 + j * 16 + l16;
        C[grow * N + gcol] = (OutT)acc[i][j][r];
      }
    }
}

// ---------------- flash attention, causal, GQA, swizzled + double-buffered ----------------
// grid (qt reversed, h, b), 256 threads = 4 waves x 16 q-rows. K/V staged via
// global_load_lds into double buffers; next tile issued BEFORE current compute so
// HBM/L2 latency hides under QK+softmax+PV; one __syncthreads per step.
__global__ __launch_bounds__(256)
void attn_kernel(const bf16* __restrict__ qkv, const bf16* __restrict__ vt,
                 bf16* __restrict__ out) {
  extern __shared__ __align__(16) bf16 smem[];
  bf16* Ks = smem;          // [2][64*128]
  bf16* Vs = smem + 16384;  // [2][128*64]
  bf16* Ps = smem + 32768;  // [4][16*64]
  const int qt = (gridDim.x - 1) - blockIdx.x;  // longest blocks first
  const int h = blockIdx.y, b = blockIdx.z;
  const int kvh = h >> 2;
  const int tid = threadIdx.x, lane = tid & 63, wave = tid >> 6;
  const int l16 = lane & 15, lhi = lane >> 4;

  bf16x8 qf[4];
  const bf16* qbase = qkv + (long)(b * SEQ + qt * 64 + wave * 16 + l16) * QKVN + h * HD + lhi * 8;
#pragma unroll
  for (int di = 0; di < 4; ++di) qf[di] = *(const bf16x8*)(qbase + di * 32);

  f32x4 oacc[8] = {};
  float m_run[4], l_run[4];
#pragma unroll
  for (int r = 0; r < 4; ++r) { m_run[r] = -1e30f; l_run[r] = 0.f; }
  const int qrow = qt * 64 + wave * 16 + lhi * 4;

  auto stageKV = [&](int buf, int step) {
    const int kv0 = step * 64;
    bf16* kd = Ks + buf * 8192;
    bf16* vd = Vs + buf * 8192;
#pragma unroll
    for (int c = 0; c < 4; ++c) {
      int chunk = wave * 4 + c;
      int krow = chunk * 4 + lhi;
      int kc16 = l16 ^ (krow & 7);
      gload_lds16(qkv + (long)(b * SEQ + kv0 + krow) * QKVN + 4096 + kvh * HD + kc16 * 8,
                  kd + chunk * 512);
      int vrow = chunk * 8 + (lane >> 3);
      int vc16 = (lane & 7) ^ (vrow & 7);
      gload_lds16(vt + ((long)(b * NKVH + kvh) * HD + vrow) * SEQ + kv0 + vc16 * 8,
                  vd + chunk * 512);
    }
  };

  const int nsteps = qt + 1;
  stageKV(0, 0);
  __syncthreads();

  for (int step = 0; step < nsteps; ++step) {
    const int kv0 = step * 64;
    const int cur = step & 1;
    if (step + 1 < nsteps) stageKV(cur ^ 1, step + 1);  // prefetch hides under compute
    const bf16* Kc = Ks + cur * 8192;
    const bf16* Vc = Vs + cur * 8192;

    // QK^T
    f32x4 s[4];
    __builtin_amdgcn_s_setprio(1);
#pragma unroll
    for (int c = 0; c < 4; ++c) {
      s[c] = (f32x4){0.f, 0.f, 0.f, 0.f};
      int krow2 = c * 16 + l16;
#pragma unroll
      for (int di = 0; di < 4; ++di) {
        bf16x8 kf = *(const bf16x8*)(Kc + krow2 * 128 + (((di * 4 + lhi) ^ (krow2 & 7))) * 8);
        s[c] = __builtin_amdgcn_mfma_f32_16x16x32_bf16(qf[di], kf, s[c], 0, 0, 0);
      }
    }
    __builtin_amdgcn_s_setprio(0);
    // scale + causal mask
#pragma unroll
    for (int c = 0; c < 4; ++c) {
      int col = kv0 + c * 16 + l16;
#pragma unroll
      for (int r = 0; r < 4; ++r) {
        float v = s[c][r] * ATT_SCALE;
        s[c][r] = (col <= qrow + r) ? v : -1e30f;
      }
    }
    // online softmax
    float alpha[4];
#pragma unroll
    for (int r = 0; r < 4; ++r) {
      float m = fmaxf(fmaxf(s[0][r], s[1][r]), fmaxf(s[2][r], s[3][r]));
#pragma unroll
      for (int off = 1; off < 16; off <<= 1)
        m = fmaxf(m, __shfl_xor(m, off, 64));
      float mn = fmaxf(m_run[r], m);
      alpha[r] = __expf(m_run[r] - mn);
      m_run[r] = mn;
      float sm = 0.f;
#pragma unroll
      for (int c = 0; c < 4; ++c) {
        float p = __expf(s[c][r] - mn);
        s[c][r] = p;
        sm += p;
      }
#pragma unroll
      for (int off = 1; off < 16; off <<= 1)
        sm += __shfl_xor(sm, off, 64);
      l_run[r] = l_run[r] * alpha[r] + sm;
    }
    // P -> wave-private LDS (swizzled)
#pragma unroll
    for (int c = 0; c < 4; ++c)
#pragma unroll
      for (int r = 0; r < 4; ++r) {
        int prow = lhi * 4 + r;
        int sl = (2 * c + (l16 >> 3)) ^ (prow & 7);
        Ps[wave * 1024 + prow * 64 + sl * 8 + (l16 & 7)] = (bf16)s[c][r];
      }
    // rescale O
#pragma unroll
    for (int dj = 0; dj < 8; ++dj)
#pragma unroll
      for (int r = 0; r < 4; ++r) oacc[dj][r] *= alpha[r];
    // PV
    __builtin_amdgcn_s_setprio(1);
#pragma unroll
    for (int kh = 0; kh < 2; ++kh) {
      bf16x8 pf = *(const bf16x8*)(Ps + wave * 1024 + l16 * 64 + (((kh * 4 + lhi) ^ (l16 & 7))) * 8);
#pragma unroll
      for (int dj = 0; dj < 8; ++dj) {
        int vrow2 = dj * 16 + l16;
        bf16x8 vf = *(const bf16x8*)(Vc + vrow2 * 64 + (((kh * 4 + lhi) ^ (vrow2 & 7))) * 8);
        oacc[dj] = __builtin_amdgcn_mfma_f32_16x16x32_bf16(pf, vf, oacc[dj], 0, 0, 0);
      }
    }
    __builtin_amdgcn_s_setprio(0);
    __syncthreads();  // drains prefetch (vmcnt0) + protects dbuf swap
  }
#pragma unroll
  for (int r = 0; r < 4; ++r) {
    float inv = 1.f / l_run[r];
    long orow = (long)(b * SEQ + qt * 64 + wave * 16 + lhi * 4 + r);
#pragma unroll
    for (int dj = 0; dj < 8; ++dj)
      out[orow * (NH * HD) + h * HD + dj * 16 + l16] = (bf16)(oacc[dj][r] * inv);
  }
}

extern "C" void kernel_launch(void* const* d_in, const int* in_sizes, int n_in,
                              void* d_out, int out_size, void* d_ws, size_t ws_size,
                              hipStream_t stream) {
  const int* positions = (const int*)d_in[0];
  const float* hidden = (const float*)d_in[1];
  const float* wq = (const float*)d_in[2];
  const float* wk = (const float*)d_in[3];
  const float* wv = (const float*)d_in[4];
  const float* wo = (const float*)d_in[5];
  float* out = (float*)d_out;
  char* ws = (char*)d_ws;

  const size_t SZ_H = (size_t)MROWS * HID * 2;
  const size_t SZ_WQKV = (size_t)QKVN * HID * 2;
  const size_t SZ_WO = (size_t)HID * HID * 2;
  bf16* h_bf = (bf16*)(ws);
  bf16* wqkvT = (bf16*)(ws + SZ_H);
  bf16* woT = (bf16*)(ws + SZ_H + SZ_WQKV);
  bf16* qkv = (bf16*)(ws + SZ_H + SZ_WQKV + SZ_WO);
  bf16* attn = h_bf;
  bf16* vtbuf = wqkvT;

  const int GEMM_SMEM = 3 * 24576 * 2;   // 147456 B
  const int ATTN_SMEM = 36864 * 2;       // 73728 B
  auto* g1 = gemm256<bf16>;
  auto* g2 = gemm256<float>;
  hipFuncSetAttribute(reinterpret_cast<const void*>(g1),
                      hipFuncAttributeMaxDynamicSharedMemorySize, GEMM_SMEM);
  hipFuncSetAttribute(reinterpret_cast<const void*>(g2),
                      hipFuncAttributeMaxDynamicSharedMemorySize, GEMM_SMEM);
  hipFuncSetAttribute(reinterpret_cast<const void*>(attn_kernel),
                      hipFuncAttributeMaxDynamicSharedMemorySize, ATTN_SMEM);

  h2b_kernel<<<(MROWS * (long)HID) / (256 * 4), 256, 0, stream>>>(hidden, h_bf);
  dim3 t32(32, 8);
  wtrans_kernel<<<dim3(HID / 32, HID / 32), t32, 0, stream>>>(wq, wqkvT, HID, HID);
  wtrans_kernel<<<dim3(1024 / 32, HID / 32), t32, 0, stream>>>(wk, wqkvT + (long)4096 * HID, HID, 1024);
  wtrans_kernel<<<dim3(1024 / 32, HID / 32), t32, 0, stream>>>(wv, wqkvT + (long)5120 * HID, HID, 1024);
  wtrans_kernel<<<dim3(HID / 32, HID / 32), t32, 0, stream>>>(wo, woT, HID, HID);
  gemm256<bf16><<<dim3(QKVN / 128, MROWS / 256), 512, GEMM_SMEM, stream>>>(h_bf, wqkvT, qkv, MROWS, QKVN, HID);
  rope_kernel<<<(MROWS * 40 * 64) / 256, 256, 0, stream>>>(qkv, positions);
  vtrans_kernel<<<dim3(SEQ / 32, HD / 32, BATCH * NKVH), t32, 0, stream>>>(qkv, vtbuf);
  attn_kernel<<<dim3(SEQ / 64, NH, BATCH), 256, ATTN_SMEM, stream>>>(qkv, vtbuf, attn);
  gemm256<float><<<dim3(HID / 128, MROWS / 256), 512, GEMM_SMEM, stream>>>(attn, woT, out, MROWS, HID, HID);
}